// Round 35
// baseline (91.433 us; speedup 1.0000x reference)
//
#include <hip/hip_runtime.h>

// R35 = R34 resubmission (round tag only). R34 hit the pod's recurring
// post-success 180s timeout (episode 4; same pattern as R3, R13/14, R25/26,
// all confirmed infra by discriminators). d_out-as-scratch audited: bounded
// writes (plane == out_size), stream-sequential, deterministic replay — no
// hang path. R34: ns=4 window widened (4th attn partial plane in d_out,
// requirement 60.3 -> 51.5MB); KVBLK=32; fallback ns=2 == R33 (90.7us).

// Problem constants
#define BB  2
#define CC  256
#define LL  4096   // 64*64 spatial tokens
#define NHD 2
#define DKD 128
#define DVD 128

#define QBLK   64
#define KVBLK  32

typedef short  short8  __attribute__((ext_vector_type(8)));
typedef float  f32x4   __attribute__((ext_vector_type(4)));
typedef unsigned short ushort4v __attribute__((ext_vector_type(4)));

__device__ __forceinline__ unsigned short f2bf(float f) {
  union { float f; unsigned u; } v; v.f = f;
  unsigned r = v.u + 0x7fffu + ((v.u >> 16) & 1u);   // RNE
  return (unsigned short)(r >> 16);
}
__device__ __forceinline__ float bf2f(unsigned short u) {
  union { unsigned u; float f; } v; v.u = ((unsigned)u) << 16;
  return v.f;
}
__device__ __forceinline__ void glds16(const unsigned short* g, unsigned short* l) {
  __builtin_amdgcn_global_load_lds(
      (const __attribute__((address_space(1))) void*)g,
      (__attribute__((address_space(3))) void*)l, 16, 0, 0);
}

// ---------------------------------------------------------------------------
// Kernel 0: precompute — z<2: transpose+convert x[b] fp32 [c][l] -> Xt bf16
// [l][c]; z==2,y==0: convert Wq/Wk/Wv -> wbf and Wm -> wmb (bf16).
// grid (128, 8, 3)  block 256.
// ---------------------------------------------------------------------------
__global__ __launch_bounds__(256) void mhsa_pre_kernel(
    const float* __restrict__ x,
    const float* __restrict__ Wq, const float* __restrict__ Wk,
    const float* __restrict__ Wv, const float* __restrict__ Wm,
    unsigned short* __restrict__ Xt, unsigned short* __restrict__ wbf,
    unsigned short* __restrict__ wmb)
{
  const int z = blockIdx.z;
  if (z == 2) {
    if (blockIdx.y) return;
    int base = blockIdx.x * 2048 + threadIdx.x;
    #pragma unroll
    for (int i = 0; i < 8; ++i) {
      int idx = base + i * 256;
      if (idx < 196608) {
        int p = idx >> 16;
        int rem = idx & 65535;
        const float* W = p == 0 ? Wq : (p == 1 ? Wk : Wv);
        wbf[idx] = f2bf(W[rem]);
      } else {
        wmb[idx - 196608] = f2bf(Wm[idx - 196608]);
      }
    }
    return;
  }
  const int b  = z;
  const int l0 = blockIdx.x * 32, c0 = blockIdx.y * 32;
  __shared__ float Ts[32][33];
  const int tid = threadIdx.x;
  const int tl  = tid & 31, tc = tid >> 5;
  const float* xb = x + (size_t)b * CC * LL;
  #pragma unroll
  for (int pp = 0; pp < 4; ++pp) {
    int c = tc + pp * 8;
    Ts[c][tl] = xb[(size_t)(c0 + c) * LL + l0 + tl];
  }
  __syncthreads();
  unsigned short* Xb = Xt + (size_t)b * LL * CC;
  #pragma unroll
  for (int pp = 0; pp < 4; ++pp) {
    int l = tc + pp * 8;
    Xb[(size_t)(l0 + l) * CC + c0 + tl] = f2bf(Ts[tl][l]);
  }
}

// ---------------------------------------------------------------------------
// Kernel 1: QKV projections via MFMA (bf16 in, fp32 acc), fused l2-norm.
// grid (64 l-tiles, 4 bh, 3 p)  block 256 (4 waves). (unchanged from R24)
// ---------------------------------------------------------------------------
__global__ __launch_bounds__(256) void mhsa_projm_kernel(
    const unsigned short* __restrict__ Xt,
    const unsigned short* __restrict__ wbf,
    const float* __restrict__ bq, const float* __restrict__ bk,
    const float* __restrict__ bv, const float* __restrict__ scale,
    unsigned short* __restrict__ qn, unsigned short* __restrict__ kn,
    unsigned short* __restrict__ vb)
{
  const int lt0 = blockIdx.x * 64;
  const int bh  = blockIdx.y;
  const int p   = blockIdx.z;
  const int h   = bh & 1, b = bh >> 1;

  const unsigned short* W = wbf + ((size_t)p * 2 + h) * (128 * 256);
  const unsigned short* X = Xt + (size_t)b * LL * CC;
  const float* bias = (p == 0 ? bq : (p == 1 ? bk : bv)) + h * 128;

  __shared__ unsigned short Ws[2][128 * 64];
  __shared__ unsigned short Xs[2][64 * 64];
  __shared__ float red[4][64];

  const int wave = threadIdx.x >> 6;
  const int lane = threadIdx.x & 63;
  const int lr = lane & 15, lc = lane >> 4;

  int offW[4], ldsW[4], offX[2], ldsX[2];
  #pragma unroll
  for (int j = 0; j < 4; ++j) {
    int ii = wave * 4 + j;
    int r  = ii * 8 + (lane >> 3);
    int c  = (lane & 7) ^ (lane >> 3);
    offW[j] = r * 256 + c * 8;
    ldsW[j] = ii * 512;
  }
  #pragma unroll
  for (int j = 0; j < 2; ++j) {
    int ii = wave * 2 + j;
    int r  = ii * 8 + (lane >> 3);
    int c  = (lane & 7) ^ (lane >> 3);
    offX[j] = (lt0 + r) * 256 + c * 8;
    ldsX[j] = ii * 512;
  }

  f32x4 acc[2][4];
  #pragma unroll
  for (int kt2 = 0; kt2 < 2; ++kt2)
    #pragma unroll
    for (int lt = 0; lt < 4; ++lt) acc[kt2][lt] = (f32x4){0.f, 0.f, 0.f, 0.f};

  #pragma unroll
  for (int j = 0; j < 4; ++j) glds16(W + offW[j], &Ws[0][ldsW[j]]);
  #pragma unroll
  for (int j = 0; j < 2; ++j) glds16(X + offX[j], &Xs[0][ldsX[j]]);
  __syncthreads();

  const int sw = lr & 7;
  int buf = 0;
  for (int step = 0; step < 4; ++step) {
    if (step < 3) {
      int c0 = (step + 1) * 64;
      #pragma unroll
      for (int j = 0; j < 4; ++j) glds16(W + c0 + offW[j], &Ws[buf ^ 1][ldsW[j]]);
      #pragma unroll
      for (int j = 0; j < 2; ++j) glds16(X + c0 + offX[j], &Xs[buf ^ 1][ldsX[j]]);
    }
    #pragma unroll
    for (int ks = 0; ks < 2; ++ks) {
      short8 af[2], bf_[4];
      #pragma unroll
      for (int kt2 = 0; kt2 < 2; ++kt2)
        af[kt2] = *reinterpret_cast<const short8*>(
            &Ws[buf][(wave * 32 + kt2 * 16 + lr) * 64 + ((ks * 4 + lc) ^ sw) * 8]);
      #pragma unroll
      for (int lt = 0; lt < 4; ++lt)
        bf_[lt] = *reinterpret_cast<const short8*>(
            &Xs[buf][(lt * 16 + lr) * 64 + ((ks * 4 + lc) ^ sw) * 8]);
      #pragma unroll
      for (int kt2 = 0; kt2 < 2; ++kt2)
        #pragma unroll
        for (int lt = 0; lt < 4; ++lt)
          acc[kt2][lt] = __builtin_amdgcn_mfma_f32_16x16x32_bf16(
              af[kt2], bf_[lt], acc[kt2][lt], 0, 0, 0);
    }
    __syncthreads();
    buf ^= 1;
  }

  #pragma unroll
  for (int kt2 = 0; kt2 < 2; ++kt2)
    #pragma unroll
    for (int r = 0; r < 4; ++r) {
      float bsv = bias[wave * 32 + kt2 * 16 + lc * 4 + r];
      #pragma unroll
      for (int lt = 0; lt < 4; ++lt) acc[kt2][lt][r] += bsv;
    }

  if (p < 2) {
    float s[4];
    #pragma unroll
    for (int lt = 0; lt < 4; ++lt) {
      float v = 0.f;
      #pragma unroll
      for (int kt2 = 0; kt2 < 2; ++kt2)
        #pragma unroll
        for (int r = 0; r < 4; ++r) v += acc[kt2][lt][r] * acc[kt2][lt][r];
      v += __shfl_xor(v, 16, 64);
      v += __shfl_xor(v, 32, 64);
      s[lt] = v;
    }
    if (lc == 0) {
      #pragma unroll
      for (int lt = 0; lt < 4; ++lt) red[wave][lt * 16 + lr] = s[lt];
    }
    __syncthreads();
    float sq = sqrtf(scale[h]);
    unsigned short* out = (p == 0 ? qn : kn) + (size_t)bh * LL * DKD;
    #pragma unroll
    for (int lt = 0; lt < 4; ++lt) {
      int l = lt * 16 + lr;
      float sum = red[0][l] + red[1][l] + red[2][l] + red[3][l];
      float nv = sq / fmaxf(sqrtf(sum), 1e-6f);
      #pragma unroll
      for (int kt2 = 0; kt2 < 2; ++kt2) {
        ushort4v pk;
        #pragma unroll
        for (int r = 0; r < 4; ++r) pk[r] = f2bf(acc[kt2][lt][r] * nv);
        *reinterpret_cast<ushort4v*>(
            out + (size_t)(lt0 + l) * DKD + wave * 32 + kt2 * 16 + lc * 4) = pk;
      }
    }
  } else {
    unsigned short* outv = vb + (size_t)bh * DVD * LL;
    #pragma unroll
    for (int kt2 = 0; kt2 < 2; ++kt2)
      #pragma unroll
      for (int r = 0; r < 4; ++r)
        #pragma unroll
        for (int lt = 0; lt < 4; ++lt)
          outv[(size_t)(wave * 32 + kt2 * 16 + lc * 4 + r) * LL + lt0 + lt * 16 + lr]
              = f2bf(acc[kt2][lt][r]);
  }
}

// ---------------------------------------------------------------------------
// Kernel 2: flash attention, KVBLK=32, runtime split count ns (2 or 4).
// Split s<3 writes ws plane pr + s*plane; split 3 writes pr3 (= d_out).
// K swizzle: chunk ^= row&7. V swizzle: chunk ^= (row>>1)&3 (involution,
// applied on global source and LDS read). STATIC-MAX softmax (M=scale[h]).
// ---------------------------------------------------------------------------
__global__ __launch_bounds__(256) void mhsa_attn_kernel(
    const unsigned short* __restrict__ qn,
    const unsigned short* __restrict__ kn,
    const unsigned short* __restrict__ vb,
    const float* __restrict__ scale,
    unsigned short* __restrict__ pr,
    unsigned short* __restrict__ pr3,
    float* __restrict__ ls,
    int kchunk)                              // LL/ns keys per split
{
  const int wgid = (blockIdx.z * gridDim.y + blockIdx.y) * gridDim.x + blockIdx.x;
  const int xcd  = wgid & 7;
  const int slot = wgid >> 3;
  const int bh   = xcd >> 1;                  // 0..3
  const int qt   = ((xcd & 1) << 5) | (slot & 31);   // 0..63
  const int s    = slot >> 5;                 // split 0..ns-1
  const int l0   = qt * QBLK;
  const int kbase = s * kchunk;
  const int tps  = kchunk / KVBLK;

  const int wave = threadIdx.x >> 6;
  const int lane = threadIdx.x & 63;
  const int lr   = lane & 15;
  const int lc   = lane >> 4;

  const unsigned short* Q = qn + (size_t)bh * LL * DKD;
  const unsigned short* K = kn + (size_t)bh * LL * DKD;
  const unsigned short* V = vb + (size_t)bh * DVD * LL;
  const float M = scale[bh & 1];              // exact row max of S

  __shared__ unsigned short Ks[2][KVBLK * DKD];   // 2 x 8KB
  __shared__ unsigned short Vs[2][DVD * KVBLK];   // 2 x 8KB
  __shared__ unsigned short plds[4][16 * 40];     // per-wave P tile (+pad)
  unsigned short* myp = plds[wave];

  const int l0w = l0 + wave * 16;
  short8 qf[4];
  #pragma unroll
  for (int ks = 0; ks < 4; ++ks)
    qf[ks] = *reinterpret_cast<const short8*>(Q + (size_t)(l0w + lr) * DKD + ks * 32 + lc * 8);

  int offK[2], offV[2], ldsOff[2];
  #pragma unroll
  for (int j = 0; j < 2; ++j) {
    int ii = wave * 2 + j;                    // 0..7
    int rK = ii * 4 + (lane >> 4);            // K row 0..31
    int cK = (lane & 15) ^ (rK & 7);          // pre-swizzled 16B chunk
    offK[j] = rK * DKD + cK * 8;
    int vV = ii * 16 + (lane >> 2);           // V row 0..127
    int cV = (lane & 3) ^ ((vV >> 1) & 3);    // pre-swizzled chunk (4/row)
    offV[j] = vV * LL + cV * 8;
    ldsOff[j] = ii * 512;                     // 1KB per instr
  }

  f32x4 racc[8];
  #pragma unroll
  for (int vt = 0; vt < 8; ++vt) racc[vt] = (f32x4){0.f, 0.f, 0.f, 0.f};
  float lsum[4] = {0.f, 0.f, 0.f, 0.f};

  #pragma unroll
  for (int j = 0; j < 2; ++j) {
    glds16(K + (size_t)kbase * DKD + offK[j], &Ks[0][ldsOff[j]]);
    glds16(V + kbase + offV[j],               &Vs[0][ldsOff[j]]);
  }
  __syncthreads();

  const int sw  = lr & 7;
  const int swV = (lr >> 1) & 3;
  int buf = 0;
  for (int t = 0; t < tps; ++t) {
    if (t + 1 < tps) {
      int m1 = kbase + (t + 1) * KVBLK;
      #pragma unroll
      for (int j = 0; j < 2; ++j) {
        glds16(K + (size_t)m1 * DKD + offK[j], &Ks[buf ^ 1][ldsOff[j]]);
        glds16(V + m1 + offV[j],               &Vs[buf ^ 1][ldsOff[j]]);
      }
    }

    f32x4 sx[2];
    #pragma unroll
    for (int ct = 0; ct < 2; ++ct) {
      f32x4 acc = (f32x4){0.f, 0.f, 0.f, 0.f};
      #pragma unroll
      for (int ks = 0; ks < 4; ++ks) {
        short8 kf = *reinterpret_cast<const short8*>(
            &Ks[buf][(ct * 16 + lr) * DKD + ((ks * 4 + lc) ^ sw) * 8]);
        acc = __builtin_amdgcn_mfma_f32_16x16x32_bf16(qf[ks], kf, acc, 0, 0, 0);
      }
      sx[ct] = acc;
    }

    #pragma unroll
    for (int ct = 0; ct < 2; ++ct) {
      #pragma unroll
      for (int r = 0; r < 4; ++r) {
        float pv = __expf(sx[ct][r] - M);
        sx[ct][r] = pv;
        lsum[r] += pv;
      }
    }

    #pragma unroll
    for (int ct = 0; ct < 2; ++ct)
      #pragma unroll
      for (int r = 0; r < 4; ++r)
        myp[(lc * 4 + r) * 40 + ct * 16 + lr] = f2bf(sx[ct][r]);

    short8 pf = *reinterpret_cast<const short8*>(&myp[lr * 40 + lc * 8]);

    #pragma unroll
    for (int vt = 0; vt < 8; ++vt) {
      short8 vf = *reinterpret_cast<const short8*>(
          &Vs[buf][(vt * 16 + lr) * KVBLK + (lc ^ swV) * 8]);
      racc[vt] = __builtin_amdgcn_mfma_f32_16x16x32_bf16(pf, vf, racc[vt], 0, 0, 0);
    }

    __syncthreads();
    buf ^= 1;
  }

  #pragma unroll
  for (int r = 0; r < 4; ++r) {
    float v = lsum[r];
    #pragma unroll
    for (int msk = 8; msk; msk >>= 1) v += __shfl_xor(v, msk, 64);
    lsum[r] = v;
  }
  if (lr == 0) {
    #pragma unroll
    for (int r = 0; r < 4; ++r)
      ls[((size_t)s * 4 + bh) * LL + l0w + lc * 4 + r] = lsum[r];
  }

  const size_t plane = (size_t)4 * DVD * LL;   // bh-major plane stride
  unsigned short* Pb = (s < 3 ? pr + (size_t)s * plane : pr3)
                       + (size_t)bh * DVD * LL;
  #pragma unroll
  for (int vt = 0; vt < 8; ++vt) {
    ushort4v pk;
    #pragma unroll
    for (int r = 0; r < 4; ++r) pk[r] = f2bf(racc[vt][r]);
    *reinterpret_cast<ushort4v*>(Pb + (size_t)(vt * 16 + lr) * LL + l0w + lc * 4) = pk;
  }
}

// ---------------------------------------------------------------------------
// Kernel 3: split-K combine + transpose: Rt[b][l][c] = (sum_s pr_s)*invL.
// Splits 0..min(ns,3)-1 from ws planes; split 3 (ns==4) from pr3 (= d_out).
// grid (128, 8, B)  block 256.
// ---------------------------------------------------------------------------
__global__ __launch_bounds__(256) void mhsa_combine_kernel(
    const unsigned short* __restrict__ pr,
    const unsigned short* __restrict__ pr3,
    const float* __restrict__ ls,
    unsigned short* __restrict__ Rt,
    int ns)
{
  const int l0 = blockIdx.x * 32;
  const int c0 = blockIdx.y * 32;
  const int b  = blockIdx.z;
  const int hh = c0 >> 7;

  __shared__ float Ts[32][33];
  __shared__ float invl[32];

  const int tid = threadIdx.x;
  const int tl  = tid & 31, tc = tid >> 5;

  if (tid < 32) {
    size_t bhl = (size_t)(b * NHD + hh) * LL + l0 + tid;
    float t = 0.f;
    for (int s = 0; s < ns; ++s) t += ls[bhl + (size_t)s * 4 * LL];
    invl[tid] = 1.f / t;
  }
  __syncthreads();

  const size_t plane = (size_t)4 * DVD * LL;
  const int nws = ns < 3 ? ns : 3;
  #pragma unroll
  for (int pp = 0; pp < 4; ++pp) {
    int cl = tc + pp * 8;
    int v  = (c0 & 127) + cl;
    size_t idx = ((size_t)(b * NHD + hh) * DVD + v) * LL + l0 + tl;
    float a = 0.f;
    for (int s = 0; s < nws; ++s) a += bf2f(pr[idx + (size_t)s * plane]);
    if (ns == 4) a += bf2f(pr3[idx]);
    Ts[cl][tl] = a * invl[tl];
  }
  __syncthreads();

  unsigned short* Rb = Rt + (size_t)b * LL * CC;
  #pragma unroll
  for (int pp = 0; pp < 4; ++pp) {
    int ll = tc + pp * 8;
    Rb[(size_t)(l0 + ll) * CC + c0 + tl] = f2bf(Ts[tl][ll]);
  }
}

// ---------------------------------------------------------------------------
// Kernel 4: merge via MFMA: out[b][o][l] = Wm(bf16).Rt + bias + x residual.
// grid (64, 2, B)  block 256 (4 waves). (unchanged from R25)
// ---------------------------------------------------------------------------
__global__ __launch_bounds__(256) void mhsa_mergem_kernel(
    const unsigned short* __restrict__ Rt,
    const unsigned short* __restrict__ wmb,
    const float* __restrict__ bm,
    const float* __restrict__ x,
    float* __restrict__ out)
{
  const int lt0 = blockIdx.x * 64;
  const int oh  = blockIdx.y;
  const int b   = blockIdx.z;

  const unsigned short* W = wmb + (size_t)oh * 128 * 256;
  const unsigned short* X = Rt + (size_t)b * LL * CC;

  __shared__ unsigned short Ws[2][128 * 64];
  __shared__ unsigned short Xs[2][64 * 64];

  const int wave = threadIdx.x >> 6;
  const int lane = threadIdx.x & 63;
  const int lr = lane & 15, lc = lane >> 4;

  int offW[4], ldsW[4], offX[2], ldsX[2];
  #pragma unroll
  for (int j = 0; j < 4; ++j) {
    int ii = wave * 4 + j;
    int r  = ii * 8 + (lane >> 3);
    int c  = (lane & 7) ^ (lane >> 3);
    offW[j] = r * 256 + c * 8;
    ldsW[j] = ii * 512;
  }
  #pragma unroll
  for (int j = 0; j < 2; ++j) {
    int ii = wave * 2 + j;
    int r  = ii * 8 + (lane >> 3);
    int c  = (lane & 7) ^ (lane >> 3);
    offX[j] = (lt0 + r) * 256 + c * 8;
    ldsX[j] = ii * 512;
  }

  f32x4 acc[2][4];
  #pragma unroll
  for (int kt2 = 0; kt2 < 2; ++kt2)
    #pragma unroll
    for (int lt = 0; lt < 4; ++lt) acc[kt2][lt] = (f32x4){0.f, 0.f, 0.f, 0.f};

  #pragma unroll
  for (int j = 0; j < 4; ++j) glds16(W + offW[j], &Ws[0][ldsW[j]]);
  #pragma unroll
  for (int j = 0; j < 2; ++j) glds16(X + offX[j], &Xs[0][ldsX[j]]);
  __syncthreads();

  const int sw = lr & 7;
  int buf = 0;
  for (int step = 0; step < 4; ++step) {
    if (step < 3) {
      int c0 = (step + 1) * 64;
      #pragma unroll
      for (int j = 0; j < 4; ++j) glds16(W + c0 + offW[j], &Ws[buf ^ 1][ldsW[j]]);
      #pragma unroll
      for (int j = 0; j < 2; ++j) glds16(X + c0 + offX[j], &Xs[buf ^ 1][ldsX[j]]);
    }
    #pragma unroll
    for (int ks = 0; ks < 2; ++ks) {
      short8 af[2], bf_[4];
      #pragma unroll
      for (int kt2 = 0; kt2 < 2; ++kt2)
        af[kt2] = *reinterpret_cast<const short8*>(
            &Ws[buf][(wave * 32 + kt2 * 16 + lr) * 64 + ((ks * 4 + lc) ^ sw) * 8]);
      #pragma unroll
      for (int lt = 0; lt < 4; ++lt)
        bf_[lt] = *reinterpret_cast<const short8*>(
            &Xs[buf][(lt * 16 + lr) * 64 + ((ks * 4 + lc) ^ sw) * 8]);
      #pragma unroll
      for (int kt2 = 0; kt2 < 2; ++kt2)
        #pragma unroll
        for (int lt = 0; lt < 4; ++lt)
          acc[kt2][lt] = __builtin_amdgcn_mfma_f32_16x16x32_bf16(
              af[kt2], bf_[lt], acc[kt2][lt], 0, 0, 0);
    }
    __syncthreads();
    buf ^= 1;
  }

  #pragma unroll
  for (int kt2 = 0; kt2 < 2; ++kt2) {
    #pragma unroll
    for (int r = 0; r < 4; ++r) {
      int o = oh * 128 + wave * 32 + kt2 * 16 + lc * 4 + r;
      float bias = bm[o];
      #pragma unroll
      for (int lt = 0; lt < 4; ++lt) {
        size_t off = ((size_t)(b * CC + o)) * LL + lt0 + lt * 16 + lr;
        out[off] = acc[kt2][lt][r] + bias + x[off];
      }
    }
  }
}

// ---------------------------------------------------------------------------
extern "C" void kernel_launch(void* const* d_in, const int* in_sizes, int n_in,
                              void* d_out, int out_size, void* d_ws, size_t ws_size,
                              hipStream_t stream) {
  const float* x     = (const float*)d_in[0];
  const float* Wq    = (const float*)d_in[1];
  const float* bq    = (const float*)d_in[2];
  const float* Wk    = (const float*)d_in[3];
  const float* bk    = (const float*)d_in[4];
  const float* Wv    = (const float*)d_in[5];
  const float* bv    = (const float*)d_in[6];
  const float* scale = (const float*)d_in[7];
  const float* Wm    = (const float*)d_in[8];
  const float* bm    = (const float*)d_in[9];
  float* out = (float*)d_out;

  const size_t nqk     = (size_t)BB * NHD * LL * DKD;      // 4.19M elems
  const size_t prPlane = (size_t)BB * NHD * DVD * LL;      // 4.19M elems/split
  const size_t lsPlane = (size_t)BB * NHD * LL;            // 65536 floats/split

  // ns=4 needs: qkv (3 planes) + 3 ws pr planes (4th lives in d_out) + 4 ls
  // planes + wmb. Deterministic in ws_size.
  size_t need4 = 3 * nqk * 2 + 3 * prPlane * 2 + 4 * lsPlane * 4 + 262144 * 2;
  const int ns = (ws_size >= need4) ? 4 : 2;
  const int nwsPlanes = (ns == 4) ? 3 : 2;
  const int kchunk = LL / ns;

  unsigned short* qn = (unsigned short*)d_ws;
  unsigned short* kn = qn + nqk;
  unsigned short* vb = kn + nqk;
  unsigned short* pr = vb + nqk;                       // ws pr planes
  unsigned short* pr3 = (unsigned short*)d_out;        // 4th plane (ns==4)
  float* lsw = (float*)(pr + (size_t)nwsPlanes * prPlane);
  unsigned short* wmb = (unsigned short*)(lsw + (size_t)ns * lsPlane);
  // Xt/wbf alias pr (dead until attn); Rt aliases qn (dead after attn)
  unsigned short* Xt  = pr;
  unsigned short* wbf = pr + (size_t)BB * LL * CC;
  unsigned short* Rt  = qn;

  mhsa_pre_kernel<<<dim3(128, 8, 3), dim3(256), 0, stream>>>(
      x, Wq, Wk, Wv, Wm, Xt, wbf, wmb);
  mhsa_projm_kernel<<<dim3(LL / 64, BB * NHD, 3), dim3(256), 0, stream>>>(
      Xt, wbf, bq, bk, bv, scale, qn, kn, vb);
  mhsa_attn_kernel<<<dim3(LL / QBLK, BB * NHD, ns), dim3(256), 0, stream>>>(
      qn, kn, vb, scale, pr, pr3, lsw, kchunk);
  mhsa_combine_kernel<<<dim3(LL / 32, CC / 32, BB), dim3(256), 0, stream>>>(
      pr, pr3, lsw, Rt, ns);
  mhsa_mergem_kernel<<<dim3(LL / 64, 2, BB), dim3(256), 0, stream>>>(
      Rt, wmb, bm, x, out);
}